// Round 5
// baseline (250.038 us; speedup 1.0000x reference)
//
#include <hip/hip_runtime.h>
#include <hip/hip_bf16.h>

#define BB 8
#define CH 256
#define C8 32
#define NP 4096   // 64*64

typedef __attribute__((ext_vector_type(8))) short bf16x8;
typedef __attribute__((ext_vector_type(4))) float f32x4;

#define MFMA16(a, b, c) __builtin_amdgcn_mfma_f32_16x16x32_bf16(a, b, c, 0, 0, 0)
#define SBAR() __builtin_amdgcn_sched_barrier(0)

#if __has_builtin(__builtin_amdgcn_exp2f)
#define EXP2(x) __builtin_amdgcn_exp2f(x)
#else
#define EXP2(x) exp2f(x)
#endif

#define LOG2E 1.44269504088896340736f

__device__ __forceinline__ void async_copy16(const void* src, void* dst_lds) {
    __builtin_amdgcn_global_load_lds(
        (const __attribute__((address_space(1))) unsigned int*)src,
        (__attribute__((address_space(3))) unsigned int*)dst_lds, 16, 0, 0);
}

__device__ __forceinline__ unsigned long long pack4bf(float a, float b, float c, float d) {
    union { __hip_bfloat16 h[4]; unsigned long long u; } p;
    p.h[0] = __float2bfloat16(a);
    p.h[1] = __float2bfloat16(b);
    p.h[2] = __float2bfloat16(c);
    p.h[3] = __float2bfloat16(d);
    return p.u;
}

// Stage a [nrows][64] bf16 LDS panel (128B rows, XOR-swizzled: data k-chunk t
// of row r lives at slot t^(r&7)) from row-major bf16 global.
__device__ __forceinline__ void stage_panel64(
    const __hip_bfloat16* __restrict__ src, int rowStride, int k0,
    __hip_bfloat16* lds, int nrows, int w, int l)
{
    const int nslots = nrows * 8;
    for (int S0 = w*64; S0 < nslots; S0 += 256) {
        int S = S0 + l;
        int r = S >> 3, s = S & 7;
        int jb = s ^ (r & 7);
        async_copy16(src + (size_t)r*rowStride + k0 + jb*8,
                     (char*)lds + (size_t)S0*16);
    }
}

// Same panel layout but from fp32 global, converted through registers.
__device__ __forceinline__ void stage_panel64_f32(
    const float* __restrict__ src, int rowStride, int k0,
    __hip_bfloat16* lds, int nrows, int tid)
{
    const int nslots = nrows * 8;
    for (int S = tid; S < nslots; S += 256) {
        int r = S >> 3, s = S & 7;
        int jb = s ^ (r & 7);
        const float* p = src + (size_t)r*rowStride + k0 + jb*8;
        float4 a = *(const float4*)p;
        float4 b = *(const float4*)(p + 4);
        union { __hip_bfloat16 h[8]; bf16x8 v; } u;
        u.h[0] = __float2bfloat16(a.x); u.h[1] = __float2bfloat16(a.y);
        u.h[2] = __float2bfloat16(a.z); u.h[3] = __float2bfloat16(a.w);
        u.h[4] = __float2bfloat16(b.x); u.h[5] = __float2bfloat16(b.y);
        u.h[6] = __float2bfloat16(b.z); u.h[7] = __float2bfloat16(b.w);
        *(bf16x8*)((char*)lds + (size_t)S*16) = u.v;
    }
}

__device__ __forceinline__ bf16x8 frag64(const __hip_bfloat16* lds, int r, int t) {
    return *(const bf16x8*)((const char*)lds + r*128 + ((t ^ (r & 7)) << 4));
}

// -------------------- K0a: weights -> bf16 ----------------------------------
__global__ __launch_bounds__(256) void convert_w(
    const float* __restrict__ wq, const float* __restrict__ wk,
    const float* __restrict__ wv,
    __hip_bfloat16* __restrict__ wqkb, __hip_bfloat16* __restrict__ wvb)
{
    int id = blockIdx.x * 256 + threadIdx.x;
    if (id < 64*256) {
        float v = (id < 32*256) ? wq[id] : wk[id - 32*256];
        wqkb[id] = __float2bfloat16(v);
    } else {
        int j = id - 64*256;
        wvb[j] = __float2bfloat16(wv[j]);
    }
}

// -------------------- K0b: x -> xbT [B][N][C] bf16 (transpose) --------------
__global__ __launch_bounds__(256) void convert_T(
    const float* __restrict__ x, __hip_bfloat16* __restrict__ xbT)
{
    int b = blockIdx.z, c0 = blockIdx.y * 64, n0 = blockIdx.x * 64;
    __shared__ float t[64][65];
    int tid = threadIdx.x;
    int nn = tid & 63, ch = tid >> 6;
    const float* xp = x + (size_t)b*CH*NP + (size_t)c0*NP + n0;
    #pragma unroll
    for (int u = 0; u < 16; ++u)
        t[ch + u*4][nn] = xp[(size_t)(ch + u*4)*NP + nn];
    __syncthreads();
    int n = tid >> 2, seg = tid & 3;
    union { __hip_bfloat16 h[16]; bf16x8 v[2]; } u16;
    #pragma unroll
    for (int u = 0; u < 16; ++u)
        u16.h[u] = __float2bfloat16(t[seg*16 + u][n]);
    __hip_bfloat16* dst = xbT + ((size_t)b*NP + n0 + n)*CH + c0 + seg*16;
    *(bf16x8*)dst = u16.v[0];
    *(bf16x8*)(dst + 8) = u16.v[1];
}

// -------------------- K1: q,k projections (MFMA) ----------------------------
// D[n][o] = sum_d xbT[n][d] * wqk[o][d];  o<32 -> q (scaled by log2e), else k.
__global__ __launch_bounds__(256) void qk_kernel(
    const __hip_bfloat16* __restrict__ xbT, const __hip_bfloat16* __restrict__ wqkb,
    const float* __restrict__ bq, const float* __restrict__ bk,
    __hip_bfloat16* __restrict__ qt, __hip_bfloat16* __restrict__ kt)
{
    const int b = blockIdx.y, n0 = blockIdx.x * 128;
    const int tid = threadIdx.x;
    const int w = tid >> 6, l = tid & 63, g = l >> 4, li = l & 15;

    __shared__ __align__(16) __hip_bfloat16 Ap[128*64];
    __shared__ __align__(16) __hip_bfloat16 Bp[64*64];

    f32x4 acc[2][4];
    #pragma unroll
    for (int mf = 0; mf < 2; ++mf)
        #pragma unroll
        for (int nf = 0; nf < 4; ++nf) acc[mf][nf] = (f32x4){0.f,0.f,0.f,0.f};

    const __hip_bfloat16* asrc = xbT + ((size_t)b*NP + n0)*CH;
    for (int kt4 = 0; kt4 < 4; ++kt4) {
        stage_panel64(asrc, CH, kt4*64, Ap, 128, w, l);
        stage_panel64(wqkb, CH, kt4*64, Bp, 64, w, l);
        __syncthreads();
        #pragma unroll
        for (int ks = 0; ks < 2; ++ks) {
            bf16x8 af[2], bf[4];
            #pragma unroll
            for (int mf = 0; mf < 2; ++mf) af[mf] = frag64(Ap, w*32 + mf*16 + li, ks*4 + g);
            #pragma unroll
            for (int nf = 0; nf < 4; ++nf) bf[nf] = frag64(Bp, nf*16 + li, ks*4 + g);
            #pragma unroll
            for (int mf = 0; mf < 2; ++mf)
                #pragma unroll
                for (int nf = 0; nf < 4; ++nf)
                    acc[mf][nf] = MFMA16(af[mf], bf[nf], acc[mf][nf]);
        }
        __syncthreads();
    }
    #pragma unroll
    for (int mf = 0; mf < 2; ++mf)
        #pragma unroll
        for (int nf = 0; nf < 4; ++nf)
            #pragma unroll
            for (int q = 0; q < 4; ++q) {
                int n = n0 + w*32 + mf*16 + g*4 + q;
                int o = nf*16 + li;
                float bias = (o < 32) ? bq[o] : bk[o - 32];
                float scl  = (o < 32) ? LOG2E : 1.0f;
                __hip_bfloat16* dst = (o < 32) ? qt : kt;
                dst[((size_t)b*NP + n)*C8 + (o & 31)] =
                    __float2bfloat16((acc[mf][nf][q] + bias) * scl);
            }
}

// -------------------- K2: v projection (MFMA) -> vb [B][C][N] ---------------
__global__ __launch_bounds__(256) void v_kernel(
    const __hip_bfloat16* __restrict__ xbT, const __hip_bfloat16* __restrict__ wvb,
    const float* __restrict__ bv, __hip_bfloat16* __restrict__ vb)
{
    const int b = blockIdx.y, n0 = blockIdx.x * 64;
    const int tid = threadIdx.x;
    const int w = tid >> 6, l = tid & 63, g = l >> 4, li = l & 15;

    __shared__ __align__(16) char smem[40960];
    __hip_bfloat16* Ap = (__hip_bfloat16*)smem;
    __hip_bfloat16* Bp = (__hip_bfloat16*)(smem + 32768);
    __hip_bfloat16* vt = (__hip_bfloat16*)smem;

    f32x4 acc[4][4];
    #pragma unroll
    for (int mf = 0; mf < 4; ++mf)
        #pragma unroll
        for (int nf = 0; nf < 4; ++nf) acc[mf][nf] = (f32x4){0.f,0.f,0.f,0.f};

    const __hip_bfloat16* bsrc = xbT + ((size_t)b*NP + n0)*CH;
    for (int kt4 = 0; kt4 < 4; ++kt4) {
        stage_panel64(wvb, CH, kt4*64, Ap, 256, w, l);
        stage_panel64(bsrc, CH, kt4*64, Bp, 64, w, l);
        __syncthreads();
        #pragma unroll
        for (int ks = 0; ks < 2; ++ks) {
            bf16x8 af[4], bf[4];
            #pragma unroll
            for (int mf = 0; mf < 4; ++mf) af[mf] = frag64(Ap, w*64 + mf*16 + li, ks*4 + g);
            #pragma unroll
            for (int nf = 0; nf < 4; ++nf) bf[nf] = frag64(Bp, nf*16 + li, ks*4 + g);
            #pragma unroll
            for (int mf = 0; mf < 4; ++mf)
                #pragma unroll
                for (int nf = 0; nf < 4; ++nf)
                    acc[mf][nf] = MFMA16(af[mf], bf[nf], acc[mf][nf]);
        }
        __syncthreads();
    }
    #pragma unroll
    for (int mf = 0; mf < 4; ++mf)
        #pragma unroll
        for (int nf = 0; nf < 4; ++nf)
            #pragma unroll
            for (int q = 0; q < 4; ++q) {
                int c = w*64 + mf*16 + g*4 + q;
                int n = nf*16 + li;
                vt[c*72 + n] = __float2bfloat16(acc[mf][nf][q] + bv[c]);
            }
    __syncthreads();
    for (int S = tid; S < 2048; S += 256) {
        int c = S >> 3, s = S & 7;
        bf16x8 v = *(const bf16x8*)((const char*)vt + c*144 + s*16);
        *(bf16x8*)(vb + ((size_t)b*CH + c)*NP + n0 + s*8) = v;
    }
}

// -------------------- K3: CAM energy partials (MFMA) ------------------------
__global__ __launch_bounds__(256) void energy_kernel(
    const float* __restrict__ x, float* __restrict__ E_part)
{
    const int rh = blockIdx.x, kp = blockIdx.y, b = blockIdx.z;
    const int tid = threadIdx.x;
    const int w = tid >> 6, l = tid & 63, g = l >> 4, li = l & 15;

    __shared__ __align__(16) __hip_bfloat16 P[256*64];

    f32x4 acc[16];
    #pragma unroll
    for (int nf = 0; nf < 16; ++nf) acc[nf] = (f32x4){0.f,0.f,0.f,0.f};

    const float* xp = x + (size_t)b*CH*NP;
    for (int kt4 = 0; kt4 < 16; ++kt4) {
        int k0 = kp*1024 + kt4*64;
        stage_panel64_f32(xp, NP, k0, P, 256, tid);
        __syncthreads();
        #pragma unroll
        for (int ks = 0; ks < 2; ++ks) {
            bf16x8 af = frag64(P, rh*64 + w*16 + li, ks*4 + g);
            #pragma unroll
            for (int nf = 0; nf < 16; ++nf) {
                bf16x8 bf = frag64(P, nf*16 + li, ks*4 + g);
                acc[nf] = MFMA16(af, bf, acc[nf]);
            }
        }
        __syncthreads();
    }
    #pragma unroll
    for (int nf = 0; nf < 16; ++nf)
        #pragma unroll
        for (int q = 0; q < 4; ++q) {
            int r = rh*64 + w*16 + g*4 + q;
            int c = nf*16 + li;
            E_part[(((size_t)b*4 + kp)*CH + r)*CH + c] = acc[nf][q];
        }
}

// -------------------- K4: softmax over C (fused partial reduce) -> bf16 -----
__global__ __launch_bounds__(256) void cam_softmax(
    const float* __restrict__ E_part, __hip_bfloat16* __restrict__ attnb)
{
    int b = blockIdx.y, r = blockIdx.x;
    int tid = threadIdx.x;
    int lane = tid & 63, wid = tid >> 6;
    const float* base = E_part + ((size_t)b*4*CH + r)*CH + tid;
    float e = base[0] + base[CH*CH] + base[2*CH*CH] + base[3*CH*CH];

    __shared__ float redm[4], reds[4];
    float m = e;
    #pragma unroll
    for (int off = 32; off >= 1; off >>= 1) m = fmaxf(m, __shfl_xor(m, off));
    if (lane == 0) redm[wid] = m;
    __syncthreads();
    m = fmaxf(fmaxf(redm[0], redm[1]), fmaxf(redm[2], redm[3]));

    float p = __expf(e - m);
    float s = p;
    #pragma unroll
    for (int off = 32; off >= 1; off >>= 1) s += __shfl_xor(s, off);
    if (lane == 0) reds[wid] = s;
    __syncthreads();
    s = reds[0] + reds[1] + reds[2] + reds[3];
    attnb[((size_t)b*CH + r)*CH + tid] = __float2bfloat16(p / s);
}

// -------------------- K5: out = gamma*(A@X) + x (MFMA) ----------------------
__global__ __launch_bounds__(256) void apply_kernel(
    const __hip_bfloat16* __restrict__ attnb, const __hip_bfloat16* __restrict__ xbT,
    const float* __restrict__ x, const float* __restrict__ gamma,
    float* __restrict__ out)
{
    const int b = blockIdx.y, n0 = blockIdx.x * 64;
    const int tid = threadIdx.x;
    const int w = tid >> 6, l = tid & 63, g = l >> 4, li = l & 15;

    __shared__ __align__(16) __hip_bfloat16 Ap[256*64];
    __shared__ __align__(16) __hip_bfloat16 Bp[64*64];

    f32x4 acc[4][4];
    #pragma unroll
    for (int mf = 0; mf < 4; ++mf)
        #pragma unroll
        for (int nf = 0; nf < 4; ++nf) acc[mf][nf] = (f32x4){0.f,0.f,0.f,0.f};

    const __hip_bfloat16* asrc = attnb + (size_t)b*CH*CH;
    const __hip_bfloat16* bsrc = xbT + ((size_t)b*NP + n0)*CH;
    for (int kt4 = 0; kt4 < 4; ++kt4) {
        stage_panel64(asrc, CH, kt4*64, Ap, 256, w, l);
        stage_panel64(bsrc, CH, kt4*64, Bp, 64, w, l);
        __syncthreads();
        #pragma unroll
        for (int ks = 0; ks < 2; ++ks) {
            bf16x8 af[4], bf[4];
            #pragma unroll
            for (int mf = 0; mf < 4; ++mf) af[mf] = frag64(Ap, w*64 + mf*16 + li, ks*4 + g);
            #pragma unroll
            for (int nf = 0; nf < 4; ++nf) bf[nf] = frag64(Bp, nf*16 + li, ks*4 + g);
            #pragma unroll
            for (int mf = 0; mf < 4; ++mf)
                #pragma unroll
                for (int nf = 0; nf < 4; ++nf)
                    acc[mf][nf] = MFMA16(af[mf], bf[nf], acc[mf][nf]);
        }
        __syncthreads();
    }
    float g0 = gamma[0];
    #pragma unroll
    for (int mf = 0; mf < 4; ++mf)
        #pragma unroll
        for (int nf = 0; nf < 4; ++nf)
            #pragma unroll
            for (int q = 0; q < 4; ++q) {
                int c = w*64 + mf*16 + g*4 + q;
                int n = n0 + nf*16 + li;
                size_t idx = ((size_t)b*CH + c)*NP + n;
                out[idx] = g0*acc[mf][nf][q] + x[idx];
            }
}

// -------------------- K6: PAM flash v4 (reg-resident V/K/Q, XCD-pinned) -----
// q pre-scaled by log2e; p = exp2(s); out[b][c][i] += (sum_j p*v[c][j])/(sum_j p)
// Only cross-wave LDS is ps (P transpose). V double-buffered in registers.

#define PAM_ITER(JT, CUR, NXT)                                                  \
    {                                                                           \
        const int jn = ((JT) + 1 < 64) ? ((JT) + 1) : 63;                       \
        /* prefetch next V tile into NXT regs + next K frag */                  \
        _Pragma("unroll")                                                       \
        for (int ks = 0; ks < 2; ++ks)                                          \
            _Pragma("unroll")                                                   \
            for (int ct = 0; ct < 4; ++ct)                                      \
                NXT[ks][ct] = *(const bf16x8*)(vbase[ct] +                      \
                    ((size_t)jn*128 + (ks*64 + g*16)));                         \
        bf16x8 kn = *(const bf16x8*)(kbase + (size_t)jn*4096);                  \
        /* QK^T on current K frag */                                            \
        f32x4 st[4];                                                            \
        _Pragma("unroll")                                                       \
        for (int t = 0; t < 4; ++t) {                                           \
            f32x4 z = (f32x4){0.f, 0.f, 0.f, 0.f};                              \
            st[t] = MFMA16(ka, qf[t], z);                                       \
        }                                                                       \
        _Pragma("unroll")                                                       \
        for (int t = 0; t < 4; ++t) {                                           \
            float p0 = EXP2(st[t][0]);                                          \
            float p1 = EXP2(st[t][1]);                                          \
            float p2 = EXP2(st[t][2]);                                          \
            float p3 = EXP2(st[t][3]);                                          \
            lacc[t] += (p0 + p1) + (p2 + p3);                                   \
            *(unsigned long long*)((char*)ps + (t*16 + li)*128 +                \
                (((2*w + (g >> 1)) ^ (li & 7)) << 4) + ((g & 1) << 3))          \
                = pack4bf(p0, p1, p2, p3);                                      \
        }                                                                       \
        /* publish ps (no vmcnt drain: V/K loads stay in flight) */             \
        asm volatile("s_waitcnt lgkmcnt(0)" ::: "memory");                      \
        SBAR();                                                                 \
        __builtin_amdgcn_s_barrier();                                           \
        SBAR();                                                                 \
        /* PV with register V (compiler inserts counted vmcnt for CUR) */       \
        _Pragma("unroll")                                                       \
        for (int ks = 0; ks < 2; ++ks) {                                        \
            bf16x8 ap[4];                                                       \
            _Pragma("unroll")                                                   \
            for (int t = 0; t < 4; ++t)                                         \
                ap[t] = *(const bf16x8*)((const char*)ps + (t*16 + li)*128 +    \
                            (((ks*4 + g) ^ (li & 7)) << 4));                    \
            _Pragma("unroll")                                                   \
            for (int ct = 0; ct < 4; ++ct)                                      \
                _Pragma("unroll")                                               \
                for (int t = 0; t < 4; ++t)                                     \
                    acc[t][ct] = MFMA16(ap[t], CUR[ks][ct], acc[t][ct]);        \
        }                                                                       \
        /* free ps */                                                           \
        SBAR();                                                                 \
        __builtin_amdgcn_s_barrier();                                           \
        SBAR();                                                                 \
        ka = kn;                                                                \
    }

__global__ __launch_bounds__(256, 2) void pam_flash(
    const __hip_bfloat16* __restrict__ qg,   // [B][N][32] (pre-scaled)
    const __hip_bfloat16* __restrict__ kg,   // [B][N][32]
    const __hip_bfloat16* __restrict__ vg,   // [B][C][N]
    float* __restrict__ out)
{
    const int bid = blockIdx.x;
    const int b   = bid & 7;                 // batch -> XCD pin (L2 residency)
    const int i0  = (bid >> 3) * 64;
    const int tid = threadIdx.x;
    const int w   = tid >> 6;
    const int l   = tid & 63;
    const int g   = l >> 4;
    const int li  = l & 15;

    __shared__ __align__(16) __hip_bfloat16 ps[64*64];   // 8KB swizzled
    __shared__ float lsh[4][64];

    // Q frags direct from global (all waves hold the same 64 rows)
    const char* qbase = (const char*)(qg + ((size_t)b*NP + i0)*C8);
    bf16x8 qf[4];
    #pragma unroll
    for (int t = 0; t < 4; ++t)
        qf[t] = *(const bf16x8*)(qbase + (t*16 + li)*64 + g*16);

    // K per-lane row pointer: rows j = j0 + w*16 + li, k-chunk g
    const char* kbase = (const char*)(kg + (size_t)b*NP*C8) + (w*16 + li)*64 + g*16;
    // V per-lane row base: c = w*64 + ct*16 + li
    const char* vbase[4];
    #pragma unroll
    for (int ct = 0; ct < 4; ++ct)
        vbase[ct] = (const char*)(vg + ((size_t)(b*CH + w*64 + ct*16 + li))*NP);

    // prologue: K tile 0 + V tile 0
    bf16x8 ka = *(const bf16x8*)(kbase);
    bf16x8 bvA[2][4], bvB[2][4];
    #pragma unroll
    for (int ks = 0; ks < 2; ++ks)
        #pragma unroll
        for (int ct = 0; ct < 4; ++ct)
            bvA[ks][ct] = *(const bf16x8*)(vbase[ct] + (ks*64 + g*16));

    f32x4 acc[4][4];
    #pragma unroll
    for (int t = 0; t < 4; ++t)
        #pragma unroll
        for (int ct = 0; ct < 4; ++ct)
            acc[t][ct] = (f32x4){0.f, 0.f, 0.f, 0.f};
    float lacc[4] = {0.f, 0.f, 0.f, 0.f};

    for (int jt = 0; jt < 64; jt += 2) {
        PAM_ITER(jt,     bvA, bvB);
        PAM_ITER(jt + 1, bvB, bvA);
    }

    // ---- reduce l across lane groups then waves ----
    #pragma unroll
    for (int t = 0; t < 4; ++t) {
        float v = lacc[t];
        v += __shfl_xor(v, 16);
        v += __shfl_xor(v, 32);
        lacc[t] = v;
    }
    if (g == 0) {
        #pragma unroll
        for (int t = 0; t < 4; ++t) lsh[w][t*16 + li] = lacc[t];
    }
    __syncthreads();

    #pragma unroll
    for (int t = 0; t < 4; ++t) {
        float linv[4];
        #pragma unroll
        for (int r = 0; r < 4; ++r) {
            int il = t*16 + g*4 + r;
            linv[r] = 1.0f / (lsh[0][il] + lsh[1][il] + lsh[2][il] + lsh[3][il]);
        }
        #pragma unroll
        for (int ct = 0; ct < 4; ++ct) {
            int c = w*64 + ct*16 + li;
            size_t base = ((size_t)b*CH + c)*NP + i0 + t*16 + g*4;
            float4 o = *(float4*)(out + base);
            o.x += acc[t][ct][0]*linv[0];
            o.y += acc[t][ct][1]*linv[1];
            o.z += acc[t][ct][2]*linv[2];
            o.w += acc[t][ct][3]*linv[3];
            *(float4*)(out + base) = o;
        }
    }
}

// ---------------------------------------------------------------------------
extern "C" void kernel_launch(void* const* d_in, const int* in_sizes, int n_in,
                              void* d_out, int out_size, void* d_ws, size_t ws_size,
                              hipStream_t stream)
{
    const float* x     = (const float*)d_in[0];
    const float* gamma = (const float*)d_in[1];
    const float* wq    = (const float*)d_in[2];
    const float* bq    = (const float*)d_in[3];
    const float* wk    = (const float*)d_in[4];
    const float* bk    = (const float*)d_in[5];
    const float* wv    = (const float*)d_in[6];
    const float* bv    = (const float*)d_in[7];
    float* out = (float*)d_out;

    char* ws = (char*)d_ws;
    __hip_bfloat16* xbT   = (__hip_bfloat16*)ws;                 ws += (size_t)BB*NP*CH*2;
    __hip_bfloat16* qtb   = (__hip_bfloat16*)ws;                 ws += (size_t)BB*NP*C8*2;
    __hip_bfloat16* ktb   = (__hip_bfloat16*)ws;                 ws += (size_t)BB*NP*C8*2;
    __hip_bfloat16* vbb   = (__hip_bfloat16*)ws;                 ws += (size_t)BB*CH*NP*2;
    __hip_bfloat16* wqkb  = (__hip_bfloat16*)ws;                 ws += 64*CH*2;
    __hip_bfloat16* wvb   = (__hip_bfloat16*)ws;                 ws += CH*CH*2;
    float*          Epart = (float*)ws;                          ws += (size_t)BB*4*CH*CH*4;
    __hip_bfloat16* attnb = (__hip_bfloat16*)ws;                 ws += (size_t)BB*CH*CH*2;

    convert_w   <<<dim3(320),        256, 0, stream>>>(wq, wk, wv, wqkb, wvb);
    convert_T   <<<dim3(64, 4, BB),  256, 0, stream>>>(x, xbT);
    qk_kernel   <<<dim3(32, BB),     256, 0, stream>>>(xbT, wqkb, bq, bk, qtb, ktb);
    v_kernel    <<<dim3(64, BB),     256, 0, stream>>>(xbT, wvb, bv, vbb);
    energy_kernel<<<dim3(4, 4, BB),  256, 0, stream>>>(x, Epart);
    cam_softmax <<<dim3(CH, BB),     256, 0, stream>>>(Epart, attnb);
    apply_kernel<<<dim3(64, BB),     256, 0, stream>>>(attnb, xbT, x, gamma, out);
    pam_flash   <<<dim3(512),        256, 0, stream>>>(qtb, ktb, vbb, out);
}

// Round 6
// 190.031 us; speedup vs baseline: 1.3158x; 1.3158x over previous
//
#include <hip/hip_runtime.h>
#include <hip/hip_bf16.h>

#define BB 8
#define CH 256
#define C8 32
#define NP 4096   // 64*64

typedef __attribute__((ext_vector_type(8))) short bf16x8;
typedef __attribute__((ext_vector_type(4))) float f32x4;

#define MFMA16(a, b, c) __builtin_amdgcn_mfma_f32_16x16x32_bf16(a, b, c, 0, 0, 0)
#define SBAR() __builtin_amdgcn_sched_barrier(0)

#if __has_builtin(__builtin_amdgcn_exp2f)
#define EXP2(x) __builtin_amdgcn_exp2f(x)
#else
#define EXP2(x) exp2f(x)
#endif

#define LOG2E 1.44269504088896340736f

__device__ __forceinline__ void async_copy16(const void* src, void* dst_lds) {
    __builtin_amdgcn_global_load_lds(
        (const __attribute__((address_space(1))) unsigned int*)src,
        (__attribute__((address_space(3))) unsigned int*)dst_lds, 16, 0, 0);
}

__device__ __forceinline__ unsigned long long pack4bf(float a, float b, float c, float d) {
    union { __hip_bfloat16 h[4]; unsigned long long u; } p;
    p.h[0] = __float2bfloat16(a);
    p.h[1] = __float2bfloat16(b);
    p.h[2] = __float2bfloat16(c);
    p.h[3] = __float2bfloat16(d);
    return p.u;
}

// Stage a [nrows][64] bf16 LDS panel (128B rows, XOR-swizzled: data k-chunk t
// of row r lives at slot t^(r&7)) from row-major bf16 global.
__device__ __forceinline__ void stage_panel64(
    const __hip_bfloat16* __restrict__ src, int rowStride, int k0,
    __hip_bfloat16* lds, int nrows, int w, int l)
{
    const int nslots = nrows * 8;
    for (int S0 = w*64; S0 < nslots; S0 += 256) {
        int S = S0 + l;
        int r = S >> 3, s = S & 7;
        int jb = s ^ (r & 7);
        async_copy16(src + (size_t)r*rowStride + k0 + jb*8,
                     (char*)lds + (size_t)S0*16);
    }
}

__device__ __forceinline__ bf16x8 frag64(const __hip_bfloat16* lds, int r, int t) {
    return *(const bf16x8*)((const char*)lds + r*128 + ((t ^ (r & 7)) << 4));
}

// -------------------- K0a: weights -> bf16 ----------------------------------
__global__ __launch_bounds__(256) void convert_w(
    const float* __restrict__ wq, const float* __restrict__ wk,
    const float* __restrict__ wv,
    __hip_bfloat16* __restrict__ wqkb, __hip_bfloat16* __restrict__ wvb)
{
    int id = blockIdx.x * 256 + threadIdx.x;
    if (id < 64*256) {
        float v = (id < 32*256) ? wq[id] : wk[id - 32*256];
        wqkb[id] = __float2bfloat16(v);
    } else {
        int j = id - 64*256;
        wvb[j] = __float2bfloat16(wv[j]);
    }
}

// ------------- K0b: x -> xbT [B][N][C] bf16 + xb [B][C][N] bf16 -------------
__global__ __launch_bounds__(256) void convert_T(
    const float* __restrict__ x, __hip_bfloat16* __restrict__ xbT,
    __hip_bfloat16* __restrict__ xb)
{
    int b = blockIdx.z, c0 = blockIdx.y * 64, n0 = blockIdx.x * 64;
    __shared__ float t[64][65];
    int tid = threadIdx.x;
    int nn = tid & 63, ch = tid >> 6;
    const float* xp = x + (size_t)b*CH*NP + (size_t)c0*NP + n0;
    #pragma unroll
    for (int u = 0; u < 16; ++u) {
        float v = xp[(size_t)(ch + u*4)*NP + nn];
        t[ch + u*4][nn] = v;
        xb[((size_t)b*CH + c0 + ch + u*4)*NP + n0 + nn] = __float2bfloat16(v);
    }
    __syncthreads();
    int n = tid >> 2, seg = tid & 3;
    union { __hip_bfloat16 h[16]; bf16x8 v[2]; } u16;
    #pragma unroll
    for (int u = 0; u < 16; ++u)
        u16.h[u] = __float2bfloat16(t[seg*16 + u][n]);
    __hip_bfloat16* dst = xbT + ((size_t)b*NP + n0 + n)*CH + c0 + seg*16;
    *(bf16x8*)dst = u16.v[0];
    *(bf16x8*)(dst + 8) = u16.v[1];
}

// -------------------- K1: q,k projections (MFMA) ----------------------------
// D[n][o] = sum_d xbT[n][d] * wqk[o][d];  o<32 -> q (scaled by log2e), else k.
__global__ __launch_bounds__(256) void qk_kernel(
    const __hip_bfloat16* __restrict__ xbT, const __hip_bfloat16* __restrict__ wqkb,
    const float* __restrict__ bq, const float* __restrict__ bk,
    __hip_bfloat16* __restrict__ qt, __hip_bfloat16* __restrict__ kt)
{
    const int b = blockIdx.y, n0 = blockIdx.x * 128;
    const int tid = threadIdx.x;
    const int w = tid >> 6, l = tid & 63, g = l >> 4, li = l & 15;

    __shared__ __align__(16) __hip_bfloat16 Ap[128*64];
    __shared__ __align__(16) __hip_bfloat16 Bp[64*64];

    f32x4 acc[2][4];
    #pragma unroll
    for (int mf = 0; mf < 2; ++mf)
        #pragma unroll
        for (int nf = 0; nf < 4; ++nf) acc[mf][nf] = (f32x4){0.f,0.f,0.f,0.f};

    const __hip_bfloat16* asrc = xbT + ((size_t)b*NP + n0)*CH;
    for (int kt4 = 0; kt4 < 4; ++kt4) {
        stage_panel64(asrc, CH, kt4*64, Ap, 128, w, l);
        stage_panel64(wqkb, CH, kt4*64, Bp, 64, w, l);
        __syncthreads();
        #pragma unroll
        for (int ks = 0; ks < 2; ++ks) {
            bf16x8 af[2], bf[4];
            #pragma unroll
            for (int mf = 0; mf < 2; ++mf) af[mf] = frag64(Ap, w*32 + mf*16 + li, ks*4 + g);
            #pragma unroll
            for (int nf = 0; nf < 4; ++nf) bf[nf] = frag64(Bp, nf*16 + li, ks*4 + g);
            #pragma unroll
            for (int mf = 0; mf < 2; ++mf)
                #pragma unroll
                for (int nf = 0; nf < 4; ++nf)
                    acc[mf][nf] = MFMA16(af[mf], bf[nf], acc[mf][nf]);
        }
        __syncthreads();
    }
    #pragma unroll
    for (int mf = 0; mf < 2; ++mf)
        #pragma unroll
        for (int nf = 0; nf < 4; ++nf)
            #pragma unroll
            for (int q = 0; q < 4; ++q) {
                int n = n0 + w*32 + mf*16 + g*4 + q;
                int o = nf*16 + li;
                float bias = (o < 32) ? bq[o] : bk[o - 32];
                float scl  = (o < 32) ? LOG2E : 1.0f;
                __hip_bfloat16* dst = (o < 32) ? qt : kt;
                dst[((size_t)b*NP + n)*C8 + (o & 31)] =
                    __float2bfloat16((acc[mf][nf][q] + bias) * scl);
            }
}

// -------------------- K2: v projection (MFMA) -> vb [B][C][N] ---------------
__global__ __launch_bounds__(256) void v_kernel(
    const __hip_bfloat16* __restrict__ xbT, const __hip_bfloat16* __restrict__ wvb,
    const float* __restrict__ bv, __hip_bfloat16* __restrict__ vb)
{
    const int b = blockIdx.y, n0 = blockIdx.x * 64;
    const int tid = threadIdx.x;
    const int w = tid >> 6, l = tid & 63, g = l >> 4, li = l & 15;

    __shared__ __align__(16) char smem[40960];
    __hip_bfloat16* Ap = (__hip_bfloat16*)smem;
    __hip_bfloat16* Bp = (__hip_bfloat16*)(smem + 32768);
    __hip_bfloat16* vt = (__hip_bfloat16*)smem;

    f32x4 acc[4][4];
    #pragma unroll
    for (int mf = 0; mf < 4; ++mf)
        #pragma unroll
        for (int nf = 0; nf < 4; ++nf) acc[mf][nf] = (f32x4){0.f,0.f,0.f,0.f};

    const __hip_bfloat16* bsrc = xbT + ((size_t)b*NP + n0)*CH;
    for (int kt4 = 0; kt4 < 4; ++kt4) {
        stage_panel64(wvb, CH, kt4*64, Ap, 256, w, l);
        stage_panel64(bsrc, CH, kt4*64, Bp, 64, w, l);
        __syncthreads();
        #pragma unroll
        for (int ks = 0; ks < 2; ++ks) {
            bf16x8 af[4], bf[4];
            #pragma unroll
            for (int mf = 0; mf < 4; ++mf) af[mf] = frag64(Ap, w*64 + mf*16 + li, ks*4 + g);
            #pragma unroll
            for (int nf = 0; nf < 4; ++nf) bf[nf] = frag64(Bp, nf*16 + li, ks*4 + g);
            #pragma unroll
            for (int mf = 0; mf < 4; ++mf)
                #pragma unroll
                for (int nf = 0; nf < 4; ++nf)
                    acc[mf][nf] = MFMA16(af[mf], bf[nf], acc[mf][nf]);
        }
        __syncthreads();
    }
    #pragma unroll
    for (int mf = 0; mf < 4; ++mf)
        #pragma unroll
        for (int nf = 0; nf < 4; ++nf)
            #pragma unroll
            for (int q = 0; q < 4; ++q) {
                int c = w*64 + mf*16 + g*4 + q;
                int n = nf*16 + li;
                vt[c*72 + n] = __float2bfloat16(acc[mf][nf][q] + bv[c]);
            }
    __syncthreads();
    for (int S = tid; S < 2048; S += 256) {
        int c = S >> 3, s = S & 7;
        bf16x8 v = *(const bf16x8*)((const char*)vt + c*144 + s*16);
        *(bf16x8*)(vb + ((size_t)b*CH + c)*NP + n0 + s*8) = v;
    }
}

// -------------------- K3: CAM energy partials (MFMA, bf16 DMA staging) ------
__global__ __launch_bounds__(256) void energy_kernel(
    const __hip_bfloat16* __restrict__ xb, float* __restrict__ E_part)
{
    const int rh = blockIdx.x, kp = blockIdx.y, b = blockIdx.z;
    const int tid = threadIdx.x;
    const int w = tid >> 6, l = tid & 63, g = l >> 4, li = l & 15;

    __shared__ __align__(16) __hip_bfloat16 P[256*64];

    f32x4 acc[16];
    #pragma unroll
    for (int nf = 0; nf < 16; ++nf) acc[nf] = (f32x4){0.f,0.f,0.f,0.f};

    const __hip_bfloat16* xp = xb + (size_t)b*CH*NP;
    for (int kt4 = 0; kt4 < 16; ++kt4) {
        int k0 = kp*1024 + kt4*64;
        stage_panel64(xp, NP, k0, P, 256, w, l);
        __syncthreads();
        #pragma unroll
        for (int ks = 0; ks < 2; ++ks) {
            bf16x8 af = frag64(P, rh*64 + w*16 + li, ks*4 + g);
            #pragma unroll
            for (int nf = 0; nf < 16; ++nf) {
                bf16x8 bf = frag64(P, nf*16 + li, ks*4 + g);
                acc[nf] = MFMA16(af, bf, acc[nf]);
            }
        }
        __syncthreads();
    }
    #pragma unroll
    for (int nf = 0; nf < 16; ++nf)
        #pragma unroll
        for (int q = 0; q < 4; ++q) {
            int r = rh*64 + w*16 + g*4 + q;
            int c = nf*16 + li;
            E_part[(((size_t)b*4 + kp)*CH + r)*CH + c] = acc[nf][q];
        }
}

// -------------------- K4: softmax over C (fused partial reduce) -> bf16 -----
__global__ __launch_bounds__(256) void cam_softmax(
    const float* __restrict__ E_part, __hip_bfloat16* __restrict__ attnb)
{
    int b = blockIdx.y, r = blockIdx.x;
    int tid = threadIdx.x;
    int lane = tid & 63, wid = tid >> 6;
    const float* base = E_part + ((size_t)b*4*CH + r)*CH + tid;
    float e = base[0] + base[CH*CH] + base[2*CH*CH] + base[3*CH*CH];

    __shared__ float redm[4], reds[4];
    float m = e;
    #pragma unroll
    for (int off = 32; off >= 1; off >>= 1) m = fmaxf(m, __shfl_xor(m, off));
    if (lane == 0) redm[wid] = m;
    __syncthreads();
    m = fmaxf(fmaxf(redm[0], redm[1]), fmaxf(redm[2], redm[3]));

    float p = __expf(e - m);
    float s = p;
    #pragma unroll
    for (int off = 32; off >= 1; off >>= 1) s += __shfl_xor(s, off);
    if (lane == 0) reds[wid] = s;
    __syncthreads();
    s = reds[0] + reds[1] + reds[2] + reds[3];
    attnb[((size_t)b*CH + r)*CH + tid] = __float2bfloat16(p / s);
}

// -------------------- K5: out = gamma*(A@X) + x (MFMA) ----------------------
__global__ __launch_bounds__(256) void apply_kernel(
    const __hip_bfloat16* __restrict__ attnb, const __hip_bfloat16* __restrict__ xbT,
    const float* __restrict__ x, const float* __restrict__ gamma,
    float* __restrict__ out)
{
    const int b = blockIdx.y, n0 = blockIdx.x * 64;
    const int tid = threadIdx.x;
    const int w = tid >> 6, l = tid & 63, g = l >> 4, li = l & 15;

    __shared__ __align__(16) __hip_bfloat16 Ap[256*64];
    __shared__ __align__(16) __hip_bfloat16 Bp[64*64];

    f32x4 acc[4][4];
    #pragma unroll
    for (int mf = 0; mf < 4; ++mf)
        #pragma unroll
        for (int nf = 0; nf < 4; ++nf) acc[mf][nf] = (f32x4){0.f,0.f,0.f,0.f};

    const __hip_bfloat16* asrc = attnb + (size_t)b*CH*CH;
    const __hip_bfloat16* bsrc = xbT + ((size_t)b*NP + n0)*CH;
    for (int kt4 = 0; kt4 < 4; ++kt4) {
        stage_panel64(asrc, CH, kt4*64, Ap, 256, w, l);
        stage_panel64(bsrc, CH, kt4*64, Bp, 64, w, l);
        __syncthreads();
        #pragma unroll
        for (int ks = 0; ks < 2; ++ks) {
            bf16x8 af[4], bf[4];
            #pragma unroll
            for (int mf = 0; mf < 4; ++mf) af[mf] = frag64(Ap, w*64 + mf*16 + li, ks*4 + g);
            #pragma unroll
            for (int nf = 0; nf < 4; ++nf) bf[nf] = frag64(Bp, nf*16 + li, ks*4 + g);
            #pragma unroll
            for (int mf = 0; mf < 4; ++mf)
                #pragma unroll
                for (int nf = 0; nf < 4; ++nf)
                    acc[mf][nf] = MFMA16(af[mf], bf[nf], acc[mf][nf]);
        }
        __syncthreads();
    }
    float g0 = gamma[0];
    #pragma unroll
    for (int mf = 0; mf < 4; ++mf)
        #pragma unroll
        for (int nf = 0; nf < 4; ++nf)
            #pragma unroll
            for (int q = 0; q < 4; ++q) {
                int c = w*64 + mf*16 + g*4 + q;
                int n = n0 + nf*16 + li;
                size_t idx = ((size_t)b*CH + c)*NP + n;
                out[idx] = g0*acc[mf][nf][q] + x[idx];
            }
}

// ---- K6: PAM flash v6 — LDS V dbuf, full-iter counted-vmcnt pipeline -------
__global__ __launch_bounds__(256, 2) void pam_flash(
    const __hip_bfloat16* __restrict__ qg,   // [B][N][32] (pre-scaled)
    const __hip_bfloat16* __restrict__ kg,   // [B][N][32]
    const __hip_bfloat16* __restrict__ vg,   // [B][C][N]
    float* __restrict__ out)
{
    const int bid = blockIdx.x;
    const int b   = bid & 7;                 // batch -> XCD pin (L2 residency)
    const int i0  = (bid >> 3) * 64;
    const int tid = threadIdx.x;
    const int w   = tid >> 6;
    const int l   = tid & 63;
    const int g   = l >> 4;
    const int li  = l & 15;

    __shared__ __align__(16) __hip_bfloat16 vs[2][256*64];  // 2x32KB swizzled
    __shared__ __align__(16) __hip_bfloat16 ps[64*64];      // 8KB swizzled
    __shared__ float lsh[4][64];                            // 1KB

    // V staging geometry: slot S16 = w*512 + it*64 + l;
    // c = w*64 + it*8 + (l>>3); jb = (l&7)^(c&7) is constant across it.
    const int c0l = (w*512 + l) >> 3;
    const int jb  = (l & 7) ^ (c0l & 7);
    const char* vbase = (const char*)vg + ((size_t)(b*CH + c0l)*NP + jb*8)*2;

    // Q frags direct from global
    const char* qbase = (const char*)(qg + ((size_t)b*NP + i0)*C8);
    bf16x8 qf[4];
    #pragma unroll
    for (int t = 0; t < 4; ++t)
        qf[t] = *(const bf16x8*)(qbase + (t*16 + li)*64 + g*16);

    // K value pipeline + prologue issues (order pinned: K0, V0x8, K1)
    const char* kptr = (const char*)(kg + (size_t)b*NP*C8) + (w*16 + li)*64 + g*16;
    bf16x8 kcur = *(const bf16x8*)(kptr);
    SBAR();
    #pragma unroll
    for (int it = 0; it < 8; ++it)
        async_copy16(vbase + (size_t)it*(8*NP*2), (char*)vs[0] + w*8192 + it*1024);
    SBAR();
    bf16x8 knext = *(const bf16x8*)(kptr + 4096);
    SBAR();

    f32x4 acc[4][4];
    #pragma unroll
    for (int t = 0; t < 4; ++t)
        #pragma unroll
        for (int ct = 0; ct < 4; ++ct)
            acc[t][ct] = (f32x4){0.f, 0.f, 0.f, 0.f};
    float lacc[4] = {0.f, 0.f, 0.f, 0.f};

    for (int jt = 0; jt < 64; ++jt) {
        // ---- B: QK^T + exp2 + ps write ----
        f32x4 st[4];
        #pragma unroll
        for (int t = 0; t < 4; ++t) {
            f32x4 z = (f32x4){0.f, 0.f, 0.f, 0.f};
            st[t] = MFMA16(kcur, qf[t], z);
        }
        #pragma unroll
        for (int t = 0; t < 4; ++t) {
            float p0 = EXP2(st[t][0]);
            float p1 = EXP2(st[t][1]);
            float p2 = EXP2(st[t][2]);
            float p3 = EXP2(st[t][3]);
            lacc[t] += (p0 + p1) + (p2 + p3);
            *(unsigned long long*)((char*)ps + (t*16 + li)*128 +
                (((2*w + (g >> 1)) ^ (li & 7)) << 4) + ((g & 1) << 3))
                = pack4bf(p0, p1, p2, p3);
        }
        asm volatile("s_waitcnt lgkmcnt(0)" ::: "memory");
        SBAR();
        __builtin_amdgcn_s_barrier();
        SBAR();

        // ---- C: wait V(jt) DMAs only (K prefetch stays in flight), PV ----
        asm volatile("s_waitcnt vmcnt(1)" ::: "memory");
        SBAR();
        {
            const char* vb = (const char*)vs[jt & 1];
            #pragma unroll
            for (int ks = 0; ks < 2; ++ks) {
                bf16x8 ap[4];
                #pragma unroll
                for (int t = 0; t < 4; ++t)
                    ap[t] = *(const bf16x8*)((const char*)ps + (t*16 + li)*128 +
                                (((ks*4 + g) ^ (li & 7)) << 4));
                #pragma unroll
                for (int ct = 0; ct < 4; ++ct) {
                    int c = w*64 + ct*16 + li;
                    bf16x8 bv = *(const bf16x8*)(vb + c*128 +
                                    (((ks*4 + g) ^ (c & 7)) << 4));
                    #pragma unroll
                    for (int t = 0; t < 4; ++t)
                        acc[t][ct] = MFMA16(ap[t], bv, acc[t][ct]);
                }
            }
        }
        SBAR();
        __builtin_amdgcn_s_barrier();
        SBAR();

        // ---- D: rotate K, issue V(jt+1) DMA + K(jt+2) load (order pinned) --
        kcur = knext;
        if (jt < 63) {
            const char* vsrc_j = vbase + (size_t)(jt + 1)*128;
            char* vdst = (char*)vs[(jt + 1) & 1] + w*8192;
            #pragma unroll
            for (int it = 0; it < 8; ++it)
                async_copy16(vsrc_j + (size_t)it*(8*NP*2), vdst + it*1024);
            SBAR();
            int kn2 = (jt + 2 < 64) ? (jt + 2) : 63;
            knext = *(const bf16x8*)(kptr + (size_t)kn2*4096);
            SBAR();
        }
    }

    // ---- reduce l across lane groups then waves ----
    #pragma unroll
    for (int t = 0; t < 4; ++t) {
        float v = lacc[t];
        v += __shfl_xor(v, 16);
        v += __shfl_xor(v, 32);
        lacc[t] = v;
    }
    if (g == 0) {
        #pragma unroll
        for (int t = 0; t < 4; ++t) lsh[w][t*16 + li] = lacc[t];
    }
    __syncthreads();

    #pragma unroll
    for (int t = 0; t < 4; ++t) {
        float linv[4];
        #pragma unroll
        for (int r = 0; r < 4; ++r) {
            int il = t*16 + g*4 + r;
            linv[r] = 1.0f / (lsh[0][il] + lsh[1][il] + lsh[2][il] + lsh[3][il]);
        }
        #pragma unroll
        for (int ct = 0; ct < 4; ++ct) {
            int c = w*64 + ct*16 + li;
            size_t base = ((size_t)b*CH + c)*NP + i0 + t*16 + g*4;
            float4 o = *(float4*)(out + base);
            o.x += acc[t][ct][0]*linv[0];
            o.y += acc[t][ct][1]*linv[1];
            o.z += acc[t][ct][2]*linv[2];
            o.w += acc[t][ct][3]*linv[3];
            *(float4*)(out + base) = o;
        }
    }
}

// ---------------------------------------------------------------------------
extern "C" void kernel_launch(void* const* d_in, const int* in_sizes, int n_in,
                              void* d_out, int out_size, void* d_ws, size_t ws_size,
                              hipStream_t stream)
{
    const float* x     = (const float*)d_in[0];
    const float* gamma = (const float*)d_in[1];
    const float* wq    = (const float*)d_in[2];
    const float* bq    = (const float*)d_in[3];
    const float* wk    = (const float*)d_in[4];
    const float* bk    = (const float*)d_in[5];
    const float* wv    = (const float*)d_in[6];
    const float* bv    = (const float*)d_in[7];
    float* out = (float*)d_out;

    char* ws = (char*)d_ws;
    __hip_bfloat16* xbT   = (__hip_bfloat16*)ws;                 ws += (size_t)BB*NP*CH*2;
    __hip_bfloat16* xb    = (__hip_bfloat16*)ws;                 ws += (size_t)BB*CH*NP*2;
    __hip_bfloat16* qtb   = (__hip_bfloat16*)ws;                 ws += (size_t)BB*NP*C8*2;
    __hip_bfloat16* ktb   = (__hip_bfloat16*)ws;                 ws += (size_t)BB*NP*C8*2;
    __hip_bfloat16* vbb   = (__hip_bfloat16*)ws;                 ws += (size_t)BB*CH*NP*2;
    __hip_bfloat16* wqkb  = (__hip_bfloat16*)ws;                 ws += 64*CH*2;
    __hip_bfloat16* wvb   = (__hip_bfloat16*)ws;                 ws += CH*CH*2;
    float*          Epart = (float*)ws;                          ws += (size_t)BB*4*CH*CH*4;
    __hip_bfloat16* attnb = (__hip_bfloat16*)ws;                 ws += (size_t)BB*CH*CH*2;

    convert_w    <<<dim3(320),        256, 0, stream>>>(wq, wk, wv, wqkb, wvb);
    convert_T    <<<dim3(64, 4, BB),  256, 0, stream>>>(x, xbT, xb);
    qk_kernel    <<<dim3(32, BB),     256, 0, stream>>>(xbT, wqkb, bq, bk, qtb, ktb);
    v_kernel     <<<dim3(64, BB),     256, 0, stream>>>(xbT, wvb, bv, vbb);
    energy_kernel<<<dim3(4, 4, BB),   256, 0, stream>>>(xb, Epart);
    cam_softmax  <<<dim3(CH, BB),     256, 0, stream>>>(Epart, attnb);
    apply_kernel <<<dim3(64, BB),     256, 0, stream>>>(attnb, xbT, x, gamma, out);
    pam_flash    <<<dim3(512),        256, 0, stream>>>(qtb, ktb, vbb, out);
}